// Round 5
// baseline (304.992 us; speedup 1.0000x reference)
//
#include <hip/hip_runtime.h>

typedef __attribute__((ext_vector_type(8)))  short short8;   // 8 bf16 (4 VGPRs)
typedef __attribute__((ext_vector_type(16))) float f32x16;   // 32x32 MFMA acc
typedef unsigned short ushort_t;
typedef unsigned int uint32;
typedef unsigned long long uint64_hip;

#define NROWS 8192
#define NCODE 8192
#define DIM   512

// ---------------- d_out layout (floats) ----------------
#define OUT_Q      0
#define OUT_LOSS   4194304
#define OUT_IDX    4194305
#define OUT_MIND   4202497
#define OUT_COMMIT 4210689

// ---------------- ws layout (floats) ----------------
#define WS_ENORM  0           // 8192 floats
#define WS_KEYS   8192        // 8192 uint64 = 16384 floats
#define WS_LPART  24576       // 2048 floats
#define WS_BHI    26624       // 8192*512 bf16 = 2097152 floats
#define WS_BLO    2123776     // same
// total 4220928 floats = 16.9 MB (< 17.38 MB proven available)

// ===========================================================================
__device__ inline uint32 bf16_rne(float f) {
    uint32 u = __float_as_uint(f);
    return (u + 0x7FFFu + ((u >> 16) & 1u)) >> 16;
}

__device__ inline void gload16(const ushort_t* g, ushort_t* l) {
    __builtin_amdgcn_global_load_lds(
        (const __attribute__((address_space(1))) void*)g,
        (__attribute__((address_space(3))) void*)l, 16, 0, 0);
}

// ===========================================================================
// Kernel 1: convert x and codebook into fragment-ordered bf16 hi/lo tiles.
// Tile = 128 rows x 16 k = 4 KB (2048 ushorts), 4 chunks of 512:
//   tile = (row>>7)*32 + (k>>4); chunk c = (row&127)>>5;
//   lane L = (row&31) + 32*((k>>3)&1), holding 8 consecutive k.
// This IS the mfma_32x32x16 A/B fragment order (verified rounds 3/4 passing).
// Also initializes the per-row argmin keys to +inf.
__global__ __launch_bounds__(256) void conv_kernel(const float* __restrict__ x,
                                                   const float* __restrict__ cb,
                                                   ushort_t* __restrict__ ahi,
                                                   ushort_t* __restrict__ alo,
                                                   ushort_t* __restrict__ bhi,
                                                   ushort_t* __restrict__ blo,
                                                   float* __restrict__ enorm,
                                                   uint64_hip* __restrict__ keys) {
    int gid  = blockIdx.x * 256 + threadIdx.x;   // 0..1048575
    if (gid < NROWS) keys[gid] = ~0ull;          // argmin key init
    bool isA = gid < 524288;
    int g    = isA ? gid : gid - 524288;
    int row  = g >> 6;
    int lane = g & 63;
    int k0   = lane * 8;
    const float* src = (isA ? x : cb) + (size_t)row * DIM + k0;
    float v[8];
    *(float4*)&v[0] = *(const float4*)src;
    *(float4*)&v[4] = *(const float4*)(src + 4);
    float s = 0.0f;
    uint32 h[8], l[8];
    #pragma unroll
    for (int i = 0; i < 8; ++i) {
        s += v[i] * v[i];
        h[i] = bf16_rne(v[i]);
        float hf = __uint_as_float(h[i] << 16);
        l[i] = bf16_rne(v[i] - hf);
    }
    int tile = (row >> 7) * 32 + (k0 >> 4);
    int c    = (row & 127) >> 5;
    int L    = (row & 31) + (((k0 >> 3) & 1) << 5);
    size_t off = (size_t)tile * 2048 + c * 512 + L * 8;   // ushort units
    uint4 ph, pl;
    ph.x = h[0] | (h[1] << 16); ph.y = h[2] | (h[3] << 16);
    ph.z = h[4] | (h[5] << 16); ph.w = h[6] | (h[7] << 16);
    pl.x = l[0] | (l[1] << 16); pl.y = l[2] | (l[3] << 16);
    pl.z = l[4] | (l[5] << 16); pl.w = l[6] | (l[7] << 16);
    if (isA) {
        *(uint4*)(ahi + off) = ph;
        *(uint4*)(alo + off) = pl;
    } else {
        *(uint4*)(bhi + off) = ph;
        *(uint4*)(blo + off) = pl;
        #pragma unroll
        for (int o = 32; o > 0; o >>= 1) s += __shfl_down(s, o);
        if (lane == 0) enorm[row] = s;
    }
}

// ===========================================================================
// Kernel 2: MFMA distance-GEMM + fused per-row argmin.
// grid 1024 (= 4 blocks/CU exactly), block 256 (4 waves, wave tile 64x64 =
// 2x2 of 32x32x16). Block tile 128 rows x 512 cols, K=512.
// LDS: 2 x 16 KB double-buffered staging (global_load_lds width 16) +
//      8 KB cand[8][128] argmin slots = 40 KB -> 4 blocks/CU.
// Per n-iter: stage 16 KB (4 DMA), 8 ds_read_b128, 12 MFMA.
// Epilogue every 32 iters: pack (dist,idx) sortable uint64 key, 3-step
// shfl_xor butterfly, owner-lane RMW into cand. Final: LDS scan + global
// atomicMin into keys[row].
// XCD swizzle: XCD j = q%8 hosts bx in [8j,8j+8) -> 2 MB A L2-resident.
__global__ __launch_bounds__(256, 4) void vq_mfma_kernel(
        const ushort_t* __restrict__ ahi, const ushort_t* __restrict__ alo,
        const ushort_t* __restrict__ bhi, const ushort_t* __restrict__ blo,
        const float* __restrict__ enorm,
        uint64_hip* __restrict__ keys) {
    __shared__ __align__(16) ushort_t smem[16384];    // 32 KB staging
    __shared__ uint64_hip cand[1024];                 // 8 KB: [slot 0..7][row 0..127]

    const int tid  = threadIdx.x;
    const int wave = tid >> 6, lane = tid & 63;
    const int l31  = lane & 31, half = lane >> 5;
    const int q  = blockIdx.x;
    const int bx = (q & 7) * 8 + (q >> 7);    // 0..63 row block; XCD = q%8
    const int by = (q >> 3) & 15;             // 0..15 col slice (512 cols)
    const int wrow = (wave >> 1) * 64;
    const int wcol = (wave & 1) * 64;
    const int so   = tid * 8;                 // staging ushort offset (16 B/thread)
    // fragment chunk offsets (ushort units) within a 16 KB staging buffer:
    // [0,2048) Ahi | [2048,4096) Alo | [4096,6144) Bhi | [6144,8192) Blo
    const int ao0 = ((wrow >> 5) + 0) * 512 + lane * 8;
    const int ao1 = ao0 + 512;
    const int bo0 = 4096 + ((wcol >> 5) + 0) * 512 + lane * 8;
    const int bo1 = bo0 + 512;

    // init cand slots
    #pragma unroll
    for (int i = 0; i < 4; ++i) cand[tid + i * 256] = ~0ull;

    f32x16 acc[2][2];
    #pragma unroll
    for (int i = 0; i < 2; ++i)
        #pragma unroll
        for (int j = 0; j < 2; ++j)
            #pragma unroll
            for (int r = 0; r < 16; ++r) acc[i][j][r] = 0.0f;

    auto stage = [&](int n, int buf) {
        const size_t at = (size_t)(bx * 32 + (n & 31)) * 2048;
        const size_t bt = (size_t)((by * 4 + (n >> 5)) * 32 + (n & 31)) * 2048;
        ushort_t* S = smem + buf * 8192;
        gload16(ahi + at + so, S + so);
        gload16(alo + at + so, S + 2048 + so);
        gload16(bhi + bt + so, S + 4096 + so);
        gload16(blo + bt + so, S + 6144 + so);
    };

    auto compute = [&](const ushort_t* S) {
        short8 ah0 = *(const short8*)&S[ao0];
        short8 ah1 = *(const short8*)&S[ao1];
        short8 al0 = *(const short8*)&S[2048 + ao0];
        short8 al1 = *(const short8*)&S[2048 + ao1];
        short8 bh0 = *(const short8*)&S[bo0];
        short8 bh1 = *(const short8*)&S[bo1];
        short8 bl0 = *(const short8*)&S[2048 + bo0];
        short8 bl1 = *(const short8*)&S[2048 + bo1];
        acc[0][0] = __builtin_amdgcn_mfma_f32_32x32x16_bf16(ah0, bh0, acc[0][0], 0, 0, 0);
        acc[0][1] = __builtin_amdgcn_mfma_f32_32x32x16_bf16(ah0, bh1, acc[0][1], 0, 0, 0);
        acc[1][0] = __builtin_amdgcn_mfma_f32_32x32x16_bf16(ah1, bh0, acc[1][0], 0, 0, 0);
        acc[1][1] = __builtin_amdgcn_mfma_f32_32x32x16_bf16(ah1, bh1, acc[1][1], 0, 0, 0);
        acc[0][0] = __builtin_amdgcn_mfma_f32_32x32x16_bf16(ah0, bl0, acc[0][0], 0, 0, 0);
        acc[0][1] = __builtin_amdgcn_mfma_f32_32x32x16_bf16(ah0, bl1, acc[0][1], 0, 0, 0);
        acc[1][0] = __builtin_amdgcn_mfma_f32_32x32x16_bf16(ah1, bl0, acc[1][0], 0, 0, 0);
        acc[1][1] = __builtin_amdgcn_mfma_f32_32x32x16_bf16(ah1, bl1, acc[1][1], 0, 0, 0);
        acc[0][0] = __builtin_amdgcn_mfma_f32_32x32x16_bf16(al0, bh0, acc[0][0], 0, 0, 0);
        acc[0][1] = __builtin_amdgcn_mfma_f32_32x32x16_bf16(al0, bh1, acc[0][1], 0, 0, 0);
        acc[1][0] = __builtin_amdgcn_mfma_f32_32x32x16_bf16(al1, bh0, acc[1][0], 0, 0, 0);
        acc[1][1] = __builtin_amdgcn_mfma_f32_32x32x16_bf16(al1, bh1, acc[1][1], 0, 0, 0);
    };

    auto epilogue = [&](int ct) {
        const int colbase = by * 512 + ct * 128 + wcol;
        const int ci0 = colbase + l31;
        const int ci1 = colbase + 32 + l31;
        const float en0 = enorm[ci0];
        const float en1 = enorm[ci1];
        #pragma unroll
        for (int ti = 0; ti < 2; ++ti) {
            #pragma unroll
            for (int reg = 0; reg < 16; ++reg) {
                float d0 = en0 - 2.0f * acc[ti][0][reg];
                float d1 = en1 - 2.0f * acc[ti][1][reg];
                uint32 u0 = __float_as_uint(d0);
                uint32 u1 = __float_as_uint(d1);
                u0 = ((int)u0 < 0) ? ~u0 : (u0 | 0x80000000u);
                u1 = ((int)u1 < 0) ? ~u1 : (u1 | 0x80000000u);
                uint64_hip k0 = ((uint64_hip)u0 << 13) | (uint32)ci0;
                uint64_hip k1 = ((uint64_hip)u1 << 13) | (uint32)ci1;
                uint64_hip k  = k0 < k1 ? k0 : k1;
                // butterfly over xor 4,8,16 -> group winner in all 8 lanes/group
                #pragma unroll
                for (int m = 4; m <= 16; m <<= 1) {
                    uint64_hip k2 = __shfl_xor(k, m);
                    if (k2 < k) k = k2;
                }
                if (l31 < 4) {
                    int row  = wrow + ti * 32 + (reg & 3) + 8 * (reg >> 2) + 4 * half;
                    int slot = (wave & 1) * 4 + l31;
                    uint64_hip old = cand[slot * 128 + row];
                    if (k < old) cand[slot * 128 + row] = k;
                }
            }
        }
        #pragma unroll
        for (int i = 0; i < 2; ++i)
            #pragma unroll
            for (int j = 0; j < 2; ++j)
                #pragma unroll
                for (int r = 0; r < 16; ++r) acc[i][j][r] = 0.0f;
    };

    stage(0, 0);
    for (int n = 0; n < 128; n += 2) {
        __syncthreads();
        if (n + 1 < 128) stage(n + 1, 1);
        compute(smem);
        // n is even -> no epilogue check needed here (epilogues at n=31,63,95,127)
        __syncthreads();
        if (n + 2 < 128) stage(n + 2, 0);
        compute(smem + 8192);
        if (((n + 1) & 31) == 31) epilogue((n + 1) >> 5);
    }

    __syncthreads();
    if (tid < 128) {
        uint64_hip best = cand[tid];
        #pragma unroll
        for (int s = 1; s < 8; ++s) {
            uint64_hip k = cand[s * 128 + tid];
            if (k < best) best = k;
        }
        atomicMin(&keys[(size_t)bx * 128 + tid], best);
    }
}

// ===========================================================================
// Kernel 3: decode key -> idx, gather codebook row, exact fp32 ||x-e||^2 ->
// min_distances + loss partials. One 64-lane group per row.
__global__ __launch_bounds__(256) void finish_kernel(const float* __restrict__ x,
                                                     const float* __restrict__ cb,
                                                     const uint64_hip* __restrict__ keys,
                                                     float* __restrict__ out_idx,
                                                     float* __restrict__ qout,
                                                     float* __restrict__ out_mind,
                                                     float* __restrict__ lpart) {
    __shared__ float sred[4];
    int row  = blockIdx.x * 4 + (threadIdx.x >> 6);
    int lane = threadIdx.x & 63;
    int idx  = (int)(keys[row] & 0x1FFFull);
    if (lane == 0) out_idx[row] = (float)idx;

    const float4* e4 = (const float4*)(cb + (size_t)idx * DIM);
    const float4* x4 = (const float4*)(x + (size_t)row * DIM);
    float4* q4 = (float4*)(qout + (size_t)row * DIM);
    float s = 0.0f;
    #pragma unroll
    for (int u = 0; u < 2; ++u) {
        float4 e  = e4[lane + u * 64];
        float4 xv = x4[lane + u * 64];
        q4[lane + u * 64] = e;
        float dx = xv.x - e.x, dy = xv.y - e.y, dz = xv.z - e.z, dw = xv.w - e.w;
        s += dx * dx + dy * dy + dz * dz + dw * dw;
    }
    #pragma unroll
    for (int o = 32; o > 0; o >>= 1) s += __shfl_down(s, o);
    if (lane == 0) { sred[threadIdx.x >> 6] = s; out_mind[row] = s; }
    __syncthreads();
    if (threadIdx.x == 0) lpart[blockIdx.x] = sred[0] + sred[1] + sred[2] + sred[3];
}

// ===========================================================================
// Kernel 4: final loss. loss_vq == loss_commit numerically => loss = 1.25*commit
__global__ __launch_bounds__(256) void loss_kernel(const float* __restrict__ lpart,
                                                   float* __restrict__ out_loss,
                                                   float* __restrict__ out_commit) {
    __shared__ float sm[256];
    float s = 0.0f;
    for (int i = threadIdx.x; i < 2048; i += 256) s += lpart[i];
    sm[threadIdx.x] = s;
    __syncthreads();
    #pragma unroll
    for (int o = 128; o > 0; o >>= 1) {
        if (threadIdx.x < o) sm[threadIdx.x] += sm[threadIdx.x + o];
        __syncthreads();
    }
    if (threadIdx.x == 0) {
        *out_commit = sm[0];
        *out_loss   = 1.25f * sm[0];
    }
}

// ===========================================================================
extern "C" void kernel_launch(void* const* d_in, const int* in_sizes, int n_in,
                              void* d_out, int out_size, void* d_ws, size_t ws_size,
                              hipStream_t stream) {
    const float* x  = (const float*)d_in[0];
    const float* cb = (const float*)d_in[1];
    float* out = (float*)d_out;
    float* ws  = (float*)d_ws;

    // A hi/lo staged in the quantized-output region (rewritten by finish_kernel)
    ushort_t* ahi = (ushort_t*)d_out;
    ushort_t* alo = (ushort_t*)d_out + 4194304;
    ushort_t* bhi = (ushort_t*)(ws + WS_BHI);
    ushort_t* blo = (ushort_t*)(ws + WS_BLO);
    float*      enorm = ws + WS_ENORM;
    uint64_hip* keys  = (uint64_hip*)(ws + WS_KEYS);
    float*      lpart = ws + WS_LPART;

    conv_kernel<<<4096, 256, 0, stream>>>(x, cb, ahi, alo, bhi, blo, enorm, keys);
    vq_mfma_kernel<<<1024, 256, 0, stream>>>(ahi, alo, bhi, blo, enorm, keys);
    finish_kernel<<<NROWS / 4, 256, 0, stream>>>(x, cb, keys,
                                                 out + OUT_IDX, out + OUT_Q,
                                                 out + OUT_MIND, lpart);
    loss_kernel<<<1, 256, 0, stream>>>(lpart, out + OUT_LOSS, out + OUT_COMMIT);
}